// Round 6
// baseline (223.385 us; speedup 1.0000x reference)
//
#include <hip/hip_runtime.h>

// Attention fwd: x@Wqkv^T -> flash attn -> @Wproj^T.  bf16 MFMA pipeline, fp32 accum.
// B=2 N=2048 C=768 H=12 Dh=64.

typedef __bf16 bf16;
typedef __attribute__((ext_vector_type(8))) __bf16 bf16x8;
typedef __attribute__((ext_vector_type(4))) __bf16 bf16x4;
typedef __attribute__((ext_vector_type(2))) __bf16 bf16x2;
typedef __attribute__((ext_vector_type(4))) float f32x4;

typedef __attribute__((address_space(1))) void gvoid;
typedef __attribute__((address_space(3))) void lvoid;

__device__ __forceinline__ void gload16(const void* g, void* l) {
  __builtin_amdgcn_global_load_lds((gvoid*)g, (lvoid*)l, 16, 0, 0);
}

// ---------------- fp32 -> bf16 conversion (x, W_qkv, W_proj) ----------------
__global__ __launch_bounds__(256) void cvt3(const float* __restrict__ x,
                                            const float* __restrict__ wq,
                                            const float* __restrict__ wp,
                                            bf16* __restrict__ xb,
                                            bf16* __restrict__ wqb,
                                            bf16* __restrict__ wpb) {
  const int N1 = 786432, N2 = 442368, N3 = 147456;  // float4 counts
  int i = blockIdx.x * 256 + threadIdx.x;
  const int stride = gridDim.x * 256;
  const int total = N1 + N2 + N3;
  for (; i < total; i += stride) {
    const float* src; bf16* dst; int j;
    if (i < N1)           { src = x;  dst = xb;  j = i; }
    else if (i < N1 + N2) { src = wq; dst = wqb; j = i - N1; }
    else                  { src = wp; dst = wpb; j = i - N1 - N2; }
    float4 v = ((const float4*)src)[j];
    bf16x4 o = { (bf16)v.x, (bf16)v.y, (bf16)v.z, (bf16)v.w };
    *(bf16x4*)(dst + (long)j * 4) = o;
  }
}

// ---------------- NT GEMM: C[M,N] = A[M,K] * B[N,K]^T, bf16 in, fp32 accum -----
template <typename OutT>
__global__ __launch_bounds__(256) void gemm_nt(const bf16* __restrict__ A,
                                               const bf16* __restrict__ B,
                                               OutT* __restrict__ C,
                                               int K, int lda, int ldb, int ldc,
                                               int mtiles) {
  __shared__ __align__(16) char smem[32768];  // [buf][A 8K | B 8K] x2
  const int tid  = threadIdx.x;
  const int lane = tid & 63;
  const int w    = tid >> 6;
  const int wm   = w >> 1, wn = w & 1;
  const int m0   = (blockIdx.x % mtiles) * 128;
  const int n0   = (blockIdx.x / mtiles) * 128;
  const int nt   = K >> 5;

  f32x4 acc[4][4] = {};

  auto stage = [&](int buf, int t) {
    const int k0 = t << 5;
    char* sA = smem + buf * 16384;
    char* sB = sA + 8192;
#pragma unroll
    for (int i = 0; i < 2; ++i) {
      const int slot = i * 256 + tid;          // 512 chunks of 16B per operand
      const int row  = slot >> 2;              // [0,128)
      const int sc   = (slot & 3) ^ (row & 3); // pre-swizzled source chunk
      gload16(A + (long)(m0 + row) * lda + k0 + sc * 8, sA + slot * 16);
      gload16(B + (long)(n0 + row) * ldb + k0 + sc * 8, sB + slot * 16);
    }
  };

  auto compute = [&](int buf) {
    const char* sA = smem + buf * 16384;
    const char* sB = sA + 8192;
    const int c = lane >> 4;
    bf16x8 a[4], b[4];
#pragma unroll
    for (int mi = 0; mi < 4; ++mi) {
      const int row = wm * 64 + mi * 16 + (lane & 15);
      a[mi] = *(const bf16x8*)(sA + row * 64 + ((c ^ (row & 3)) << 4));
    }
#pragma unroll
    for (int ni = 0; ni < 4; ++ni) {
      const int row = wn * 64 + ni * 16 + (lane & 15);
      b[ni] = *(const bf16x8*)(sB + row * 64 + ((c ^ (row & 3)) << 4));
    }
#pragma unroll
    for (int mi = 0; mi < 4; ++mi)
#pragma unroll
      for (int ni = 0; ni < 4; ++ni)
        acc[mi][ni] = __builtin_amdgcn_mfma_f32_16x16x32_bf16(a[mi], b[ni], acc[mi][ni], 0, 0, 0);
  };

  stage(0, 0);
  __syncthreads();
  for (int t = 0; t < nt; ++t) {
    if (t + 1 < nt) stage((t + 1) & 1, t + 1);
    compute(t & 1);
    __syncthreads();
  }

#pragma unroll
  for (int mi = 0; mi < 4; ++mi)
#pragma unroll
    for (int ni = 0; ni < 4; ++ni)
#pragma unroll
      for (int r = 0; r < 4; ++r) {
        const int row = m0 + wm * 64 + mi * 16 + (lane >> 4) * 4 + r;
        const int col = n0 + wn * 64 + ni * 16 + (lane & 15);
        C[(long)row * ldc + col] = (OutT)acc[mi][ni][r];
      }
}

// ---------------- flash attention fwd (8-wave, KV-split halves) --------------
// grid (32 qtiles x 64 rows, 24 bh); block 512 = 8 waves.
// Waves 0-3: kv [0,1024) for q-subtiles 0-3; waves 4-7: kv [1024,2048).
// Each half: private double-buffered swizzled V in LDS (8KB x2), 16 KV tiles.
// Swapped QK^T (lane owns a q-col), in-register P, shuffle-free steady-state
// softmax (lane-local defer-max check; row-sum reduce deferred to epilogue).
// Halves merged at the end via LDS (log2-domain flash merge).
__global__ __launch_bounds__(512, 6) void attn_fwd(const bf16* __restrict__ qkv,
                                                   bf16* __restrict__ O) {
  __shared__ __align__(16) char Vs[32768];  // [half][buf][ Vt 64d x 128B swizzled ]
  const int tid  = threadIdx.x;
  const int lane = tid & 63;
  const int w    = tid >> 6;
  const int l15  = lane & 15;
  const int l4   = lane >> 4;
  const int hh   = w >> 2;   // kv half
  const int qs   = w & 3;    // q sub-block (16 rows)
  const int b    = blockIdx.y / 12;
  const int h    = blockIdx.y % 12;
  const int q0   = blockIdx.x * 64;
  const unsigned base = (unsigned)b * 2048u * 2304u;
  const int h64  = h * 64;
  const unsigned VSTEP = 64u * 2304u;
  const int kvbase = hh * 1024;

  char* Vh = Vs + hh * 16384;

  // Q fragments, pre-scaled by SCALE*log2(e) = 0.125 * 1.4426950
  bf16x8 qf[2];
  {
    const bf16* qp = qkv + base + (unsigned)(q0 + qs * 16 + l15) * 2304u + h64 + l4 * 8;
#pragma unroll
    for (int kk = 0; kk < 2; ++kk) {
      bf16x8 t = *(const bf16x8*)(qp + kk * 32);
#pragma unroll
      for (int j = 0; j < 8; ++j) qf[kk][j] = (bf16)((float)t[j] * 0.18033688f);
    }
  }

  // K row offsets (A-fragments from global; L2/L3-resident)
  unsigned koff[4];
#pragma unroll
  for (int f = 0; f < 4; ++f)
    koff[f] = base + (unsigned)(kvbase + f * 16 + l15) * 2304u + 768u + h64 + l4 * 8;

  // V staging: half's 256 threads; gt -> kv pair p = gt&31 (rows 2p,2p+1),
  // d-block dblk = gt>>5.  Writes lane-private bf16x2 dwords (kv contiguous).
  const int gt   = tid & 255;
  const int p    = gt & 31;
  const int dblk = gt >> 5;  // [0,8)
  const int pc   = p >> 2;
  const int cw   = (p & 3) * 4;
  unsigned voff = base + (unsigned)(kvbase + 2 * p) * 2304u + 1536u + h64 + dblk * 8;

  auto vt_write = [&](char* W, const bf16x8& r0, const bf16x8& r1) {
#pragma unroll
    for (int j = 0; j < 8; ++j) {
      const int d = dblk * 8 + j;  // d&7 == j
      bf16x2 t2 = { r0[j], r1[j] };
      *(bf16x2*)(W + d * 128 + ((pc ^ j) << 4) + cw) = t2;
    }
  };

  float m = -1e30f, lsum = 0.f;   // lsum = lane-local PARTIAL row-sum
  f32x4 o[4] = {};

  // prologue: stage this half's V tile 0 into buf 0
  {
    bf16x8 r0 = *(const bf16x8*)(qkv + voff);
    bf16x8 r1 = *(const bf16x8*)(qkv + voff + 2304);
    voff += VSTEP;
    vt_write(Vh, r0, r1);
  }
  __syncthreads();

  for (int t = 0; t < 16; ++t) {
    const int buf = t & 1;
    const bool pre = (t < 15);

    // (a) issue next V tile's global loads early (written after PV)
    bf16x8 nr0, nr1;
    if (pre) {
      nr0 = *(const bf16x8*)(qkv + voff);
      nr1 = *(const bf16x8*)(qkv + voff + 2304);
      voff += VSTEP;
    }

    // (b) S^T = K Q^T : rows = kv (l4*4+r per 16-frag f), cols = q (l15)
    f32x4 s[4];
    __builtin_amdgcn_s_setprio(1);
#pragma unroll
    for (int f = 0; f < 4; ++f) {
      bf16x8 k0 = *(const bf16x8*)(qkv + koff[f]);
      bf16x8 k1 = *(const bf16x8*)(qkv + koff[f] + 32);
      f32x4 acc = {};
      acc = __builtin_amdgcn_mfma_f32_16x16x32_bf16(k0, qf[0], acc, 0, 0, 0);
      acc = __builtin_amdgcn_mfma_f32_16x16x32_bf16(k1, qf[1], acc, 0, 0, 0);
      s[f] = acc;
      koff[f] += VSTEP;
    }
    __builtin_amdgcn_s_setprio(0);

    // (c) shuffle-free steady-state softmax (exp2 domain).
    // lane-local tile max over this lane's 16 kv slots
    float tm = s[0][0];
#pragma unroll
    for (int f = 0; f < 4; ++f)
#pragma unroll
      for (int r = 0; r < 4; ++r) tm = fmaxf(tm, s[f][r]);

    // defer-max: only when some lane's slots outgrow running max by >8
    if (__any(tm > m + 8.f)) {
      tm = fmaxf(tm, __shfl_xor(tm, 16));   // full per-q-col tile max
      tm = fmaxf(tm, __shfl_xor(tm, 32));
      const float mn = fmaxf(m, tm);
      const float alpha = __builtin_amdgcn_exp2f(m - mn);
      m = mn;
      lsum *= alpha;
      f32x4 av;
#pragma unroll
      for (int r = 0; r < 4; ++r) av[r] = __shfl(alpha, l4 * 4 + r);
#pragma unroll
      for (int fd = 0; fd < 4; ++fd) o[fd] *= av;
    }

    // p = 2^(s - m); accumulate lane-local partial row-sum only
    float rs = 0.f;
#pragma unroll
    for (int f = 0; f < 4; ++f)
#pragma unroll
      for (int r = 0; r < 4; ++r) {
        const float pv = __builtin_amdgcn_exp2f(s[f][r] - m);
        s[f][r] = pv;
        rs += pv;
      }
    lsum += rs;

    // P A-fragments (k-slot j of mfma kk -> kv = (kk*2+(j>>2))*16 + l4*4 + (j&3))
    bf16x8 pa[2];
#pragma unroll
    for (int kk = 0; kk < 2; ++kk)
#pragma unroll
      for (int j = 0; j < 8; ++j)
        pa[kk][j] = (bf16)s[kk * 2 + (j >> 2)][j & 3];

    // (e) O += P V : B-frags from swizzled Vt with the SAME permuted-kv mapping
    const char* Vb = Vh + buf * 8192;
    const int sub = (l4 & 1) * 8;
    __builtin_amdgcn_s_setprio(1);
#pragma unroll
    for (int kk = 0; kk < 2; ++kk) {
      const int cr0 = kk * 4 + (l4 >> 1);
#pragma unroll
      for (int fd = 0; fd < 4; ++fd) {
        const int d = fd * 16 + l15;
        const char* row = Vb + d * 128;
        bf16x4 lo = *(const bf16x4*)(row + ((cr0 ^ (d & 7)) << 4) + sub);
        bf16x4 hi = *(const bf16x4*)(row + (((cr0 + 2) ^ (d & 7)) << 4) + sub);
        bf16x8 vb = __builtin_shufflevector(lo, hi, 0, 1, 2, 3, 4, 5, 6, 7);
        o[fd] = __builtin_amdgcn_mfma_f32_16x16x32_bf16(pa[kk], vb, o[fd], 0, 0, 0);
      }
    }
    __builtin_amdgcn_s_setprio(0);

    // (d) late-write next V tile into the other buffer
    if (pre) vt_write(Vh + (buf ^ 1) * 8192, nr0, nr1);

    __syncthreads();
  }
  // final barrier passed: all PV reads done -> Vs reusable as combine buffer

  // epilogue: reduce the 4 lane-group partial row-sums (per q-col)
  lsum += __shfl_xor(lsum, 16);
  lsum += __shfl_xor(lsum, 32);

  // ---- merge halves (log2-domain flash merge) via LDS ----
  float* cb = (float*)Vs;                     // [qs][16 rows][64 d] fp32 = 16KB
  float* cm = (float*)(Vs + 16384);           // m  [qs][16]
  float* cl = (float*)(Vs + 16384 + 256);     // l  [qs][16]
  if (hh == 1) {
#pragma unroll
    for (int fd = 0; fd < 4; ++fd)
#pragma unroll
      for (int r = 0; r < 4; ++r)
        cb[qs * 1024 + (l4 * 4 + r) * 64 + fd * 16 + l15] = o[fd][r];
    if (l4 == 0) { cm[qs * 16 + l15] = m; cl[qs * 16 + l15] = lsum; }
  }
  __syncthreads();
  if (hh == 0) {
    const float mB = cm[qs * 16 + l15];
    const float lB = cl[qs * 16 + l15];
    const float M  = fmaxf(m, mB);
    const float sA = __builtin_amdgcn_exp2f(m - M);
    const float sB = __builtin_amdgcn_exp2f(mB - M);
    const float inv = 1.0f / (lsum * sA + lB * sB);
    const float fAq = sA * inv, fBq = sB * inv;
    f32x4 fA, fB;
#pragma unroll
    for (int r = 0; r < 4; ++r) {
      fA[r] = __shfl(fAq, l4 * 4 + r);
      fB[r] = __shfl(fBq, l4 * 4 + r);
    }
    bf16* op = O + ((long)(b * 2048 + q0 + qs * 16 + l4 * 4)) * 768 + h64 + l15;
#pragma unroll
    for (int fd = 0; fd < 4; ++fd)
#pragma unroll
      for (int r = 0; r < 4; ++r) {
        const float v = o[fd][r] * fA[r] +
                        cb[qs * 1024 + (l4 * 4 + r) * 64 + fd * 16 + l15] * fB[r];
        op[(long)r * 768 + fd * 16] = (bf16)v;
      }
  }
}

// ---------------- launch ----------------
extern "C" void kernel_launch(void* const* d_in, const int* in_sizes, int n_in,
                              void* d_out, int out_size, void* d_ws, size_t ws_size,
                              hipStream_t stream) {
  const float* x  = (const float*)d_in[0];
  const float* wq = (const float*)d_in[1];
  const float* wp = (const float*)d_in[2];
  float* out = (float*)d_out;
  char* ws = (char*)d_ws;

  bf16* xb   = (bf16*)(ws + 0);
  bf16* wqb  = (bf16*)(ws + 6291456);
  bf16* wpb  = (bf16*)(ws + 9830400);
  bf16* qkvb = (bf16*)(ws + 11010048);
  bf16* ob   = (bf16*)(ws + 29884416);

  cvt3<<<dim3(1024), dim3(256), 0, stream>>>(x, wq, wp, xb, wqb, wpb);
  // qkv = x @ Wqkv^T : M=4096 N=2304 K=768
  gemm_nt<bf16><<<dim3(576), dim3(256), 0, stream>>>(xb, wqb, qkvb, 768, 768, 768, 2304, 32);
  attn_fwd<<<dim3(32, 24), dim3(512), 0, stream>>>(qkvb, ob);
  // out = attn_out @ Wproj^T : M=4096 N=768 K=768, fp32 out
  gemm_nt<float><<<dim3(192), dim3(256), 0, stream>>>(ob, wpb, out, 768, 768, 768, 768, 32);
}

// Round 7
// 160.922 us; speedup vs baseline: 1.3882x; 1.3882x over previous
//
#include <hip/hip_runtime.h>

// Attention fwd: x@Wqkv^T -> flash attn -> @Wproj^T.  bf16 MFMA pipeline, fp32 accum.
// B=2 N=2048 C=768 H=12 Dh=64.

typedef __bf16 bf16;
typedef __attribute__((ext_vector_type(8))) __bf16 bf16x8;
typedef __attribute__((ext_vector_type(4))) __bf16 bf16x4;
typedef __attribute__((ext_vector_type(2))) __bf16 bf16x2;
typedef __attribute__((ext_vector_type(4))) float f32x4;

typedef __attribute__((address_space(1))) void gvoid;
typedef __attribute__((address_space(3))) void lvoid;

__device__ __forceinline__ void gload16(const void* g, void* l) {
  __builtin_amdgcn_global_load_lds((gvoid*)g, (lvoid*)l, 16, 0, 0);
}

// ---------------- fp32 -> bf16 conversion (x, W_qkv, W_proj) ----------------
__global__ __launch_bounds__(256) void cvt3(const float* __restrict__ x,
                                            const float* __restrict__ wq,
                                            const float* __restrict__ wp,
                                            bf16* __restrict__ xb,
                                            bf16* __restrict__ wqb,
                                            bf16* __restrict__ wpb) {
  const int N1 = 786432, N2 = 442368, N3 = 147456;  // float4 counts
  int i = blockIdx.x * 256 + threadIdx.x;
  const int stride = gridDim.x * 256;
  const int total = N1 + N2 + N3;
  for (; i < total; i += stride) {
    const float* src; bf16* dst; int j;
    if (i < N1)           { src = x;  dst = xb;  j = i; }
    else if (i < N1 + N2) { src = wq; dst = wqb; j = i - N1; }
    else                  { src = wp; dst = wpb; j = i - N1 - N2; }
    float4 v = ((const float4*)src)[j];
    bf16x4 o = { (bf16)v.x, (bf16)v.y, (bf16)v.z, (bf16)v.w };
    *(bf16x4*)(dst + (long)j * 4) = o;
  }
}

// ---------------- NT GEMM: C[M,N] = A[M,K] * B[N,K]^T, bf16 in, fp32 accum -----
template <typename OutT>
__global__ __launch_bounds__(256) void gemm_nt(const bf16* __restrict__ A,
                                               const bf16* __restrict__ B,
                                               OutT* __restrict__ C,
                                               int K, int lda, int ldb, int ldc,
                                               int mtiles) {
  __shared__ __align__(16) char smem[32768];  // [buf][A 8K | B 8K] x2
  const int tid  = threadIdx.x;
  const int lane = tid & 63;
  const int w    = tid >> 6;
  const int wm   = w >> 1, wn = w & 1;
  const int m0   = (blockIdx.x % mtiles) * 128;
  const int n0   = (blockIdx.x / mtiles) * 128;
  const int nt   = K >> 5;

  f32x4 acc[4][4] = {};

  auto stage = [&](int buf, int t) {
    const int k0 = t << 5;
    char* sA = smem + buf * 16384;
    char* sB = sA + 8192;
#pragma unroll
    for (int i = 0; i < 2; ++i) {
      const int slot = i * 256 + tid;          // 512 chunks of 16B per operand
      const int row  = slot >> 2;              // [0,128)
      const int sc   = (slot & 3) ^ (row & 3); // pre-swizzled source chunk
      gload16(A + (long)(m0 + row) * lda + k0 + sc * 8, sA + slot * 16);
      gload16(B + (long)(n0 + row) * ldb + k0 + sc * 8, sB + slot * 16);
    }
  };

  auto compute = [&](int buf) {
    const char* sA = smem + buf * 16384;
    const char* sB = sA + 8192;
    const int c = lane >> 4;
    bf16x8 a[4], b[4];
#pragma unroll
    for (int mi = 0; mi < 4; ++mi) {
      const int row = wm * 64 + mi * 16 + (lane & 15);
      a[mi] = *(const bf16x8*)(sA + row * 64 + ((c ^ (row & 3)) << 4));
    }
#pragma unroll
    for (int ni = 0; ni < 4; ++ni) {
      const int row = wn * 64 + ni * 16 + (lane & 15);
      b[ni] = *(const bf16x8*)(sB + row * 64 + ((c ^ (row & 3)) << 4));
    }
#pragma unroll
    for (int mi = 0; mi < 4; ++mi)
#pragma unroll
      for (int ni = 0; ni < 4; ++ni)
        acc[mi][ni] = __builtin_amdgcn_mfma_f32_16x16x32_bf16(a[mi], b[ni], acc[mi][ni], 0, 0, 0);
  };

  stage(0, 0);
  __syncthreads();
  for (int t = 0; t < nt; ++t) {
    if (t + 1 < nt) stage((t + 1) & 1, t + 1);
    compute(t & 1);
    __syncthreads();
  }

#pragma unroll
  for (int mi = 0; mi < 4; ++mi)
#pragma unroll
    for (int ni = 0; ni < 4; ++ni)
#pragma unroll
      for (int r = 0; r < 4; ++r) {
        const int row = m0 + wm * 64 + mi * 16 + (lane >> 4) * 4 + r;
        const int col = n0 + wn * 64 + ni * 16 + (lane & 15);
        C[(long)row * ldc + col] = (OutT)acc[mi][ni][r];
      }
}

// ---------------- flash attention fwd (K through LDS) ------------------------
// grid (32 qtiles, 24 bh); block 256 = 4 waves, wave owns 16 q-rows, full KV.
// K tiles staged ONCE per block via coalesced global_load_lds into XOR-swizzled
// double-buffered LDS (all 4 waves share); A-fragments via ds_read_b128.
// V reg-staged + swizzled transpose writes (R3-verified). Swapped QK^T,
// in-register P, shuffle-free defer-max softmax (R6-verified).
__global__ __launch_bounds__(256, 3) void attn_fwd(const bf16* __restrict__ qkv,
                                                   bf16* __restrict__ O) {
  __shared__ __align__(16) char Ks[16384];  // 2 bufs x K[64 rows][128B] swizzled
  __shared__ __align__(16) char Vs[16384];  // 2 bufs x Vt[64 d][128B kv] swizzled
  const int tid  = threadIdx.x;
  const int lane = tid & 63;
  const int w    = tid >> 6;
  const int l15  = lane & 15;
  const int l4   = lane >> 4;
  const int b    = blockIdx.y / 12;
  const int h    = blockIdx.y % 12;
  const int q0   = blockIdx.x * 64;
  const unsigned base = (unsigned)b * 2048u * 2304u;
  const int h64  = h * 64;
  const unsigned VSTEP = 64u * 2304u;

  // Q fragments, pre-scaled by SCALE*log2(e) = 0.125 * 1.4426950
  bf16x8 qf[2];
  {
    const bf16* qp = qkv + base + (unsigned)(q0 + w * 16 + l15) * 2304u + h64 + l4 * 8;
#pragma unroll
    for (int kk = 0; kk < 2; ++kk) {
      bf16x8 t = *(const bf16x8*)(qp + kk * 32);
#pragma unroll
      for (int j = 0; j < 8; ++j) qf[kk][j] = (bf16)((float)t[j] * 0.18033688f);
    }
  }

  // K staging: 2 rounds x 256 threads of 16B chunks; slot s -> row=s>>3, c'=s&7.
  // LDS[row][c'] = G[row][c' ^ (row&7)]  (pre-swizzled source, linear LDS dest)
  const int krow0 = tid >> 3;                         // round 0 row
  const int kc0   = (tid & 7) ^ (krow0 & 7);
  const int krow1 = (256 + tid) >> 3;                 // round 1 row
  const int kc1   = (tid & 7) ^ (krow1 & 7);
  unsigned koff0 = base + (unsigned)krow0 * 2304u + 768u + h64 + kc0 * 8;
  unsigned koff1 = base + (unsigned)krow1 * 2304u + 768u + h64 + kc1 * 8;

  auto k_stage = [&](int buf) {
    gload16(qkv + koff0, Ks + buf * 8192 + tid * 16);
    gload16(qkv + koff1, Ks + buf * 8192 + 4096 + tid * 16);
    koff0 += VSTEP;
    koff1 += VSTEP;
  };

  // V staging: thread -> kv pair p = tid&31 (rows 2p,2p+1), d-block dblk = tid>>5.
  const int p    = tid & 31;
  const int dblk = tid >> 5;  // [0,8)
  const int pc   = p >> 2;
  const int cw   = (p & 3) * 4;
  unsigned voff = base + (unsigned)(2 * p) * 2304u + 1536u + h64 + dblk * 8;

  auto vt_write = [&](char* W, const bf16x8& r0, const bf16x8& r1) {
#pragma unroll
    for (int j = 0; j < 8; ++j) {
      const int d = dblk * 8 + j;  // d&7 == j
      bf16x2 t2 = { r0[j], r1[j] };
      *(bf16x2*)(W + d * 128 + ((pc ^ j) << 4) + cw) = t2;
    }
  };

  float m = -1e30f, lsum = 0.f;   // lsum = lane-local PARTIAL row-sum
  f32x4 o[4] = {};

  // prologue: stage K tile 0 + V tile 0 into buf 0
  k_stage(0);
  {
    bf16x8 r0 = *(const bf16x8*)(qkv + voff);
    bf16x8 r1 = *(const bf16x8*)(qkv + voff + 2304);
    voff += VSTEP;
    vt_write(Vs, r0, r1);
  }
  __syncthreads();

  for (int t = 0; t < 32; ++t) {
    const int buf = t & 1;
    const bool pre = (t < 31);

    // (a) issue next tile's K stage (async -> LDS) and V reg loads early
    bf16x8 nr0, nr1;
    if (pre) {
      k_stage(buf ^ 1);
      nr0 = *(const bf16x8*)(qkv + voff);
      nr1 = *(const bf16x8*)(qkv + voff + 2304);
      voff += VSTEP;
    }

    // (b) S^T = K Q^T : A-frags from swizzled K LDS (row = f*16+l15, chunk kk*4+l4)
    const char* Kb = Ks + buf * 8192;
    f32x4 s[4];
    __builtin_amdgcn_s_setprio(1);
#pragma unroll
    for (int f = 0; f < 4; ++f) {
      const int row = f * 16 + l15;
      const char* krow = Kb + row * 128;
      bf16x8 k0 = *(const bf16x8*)(krow + (((0 + l4) ^ (row & 7)) << 4));
      bf16x8 k1 = *(const bf16x8*)(krow + (((4 + l4) ^ (row & 7)) << 4));
      f32x4 acc = {};
      acc = __builtin_amdgcn_mfma_f32_16x16x32_bf16(k0, qf[0], acc, 0, 0, 0);
      acc = __builtin_amdgcn_mfma_f32_16x16x32_bf16(k1, qf[1], acc, 0, 0, 0);
      s[f] = acc;
    }
    __builtin_amdgcn_s_setprio(0);

    // (c) shuffle-free steady-state softmax (exp2 domain)
    float tm = s[0][0];
#pragma unroll
    for (int f = 0; f < 4; ++f)
#pragma unroll
      for (int r = 0; r < 4; ++r) tm = fmaxf(tm, s[f][r]);

    if (__any(tm > m + 8.f)) {
      tm = fmaxf(tm, __shfl_xor(tm, 16));
      tm = fmaxf(tm, __shfl_xor(tm, 32));
      const float mn = fmaxf(m, tm);
      const float alpha = __builtin_amdgcn_exp2f(m - mn);
      m = mn;
      lsum *= alpha;
      f32x4 av;
#pragma unroll
      for (int r = 0; r < 4; ++r) av[r] = __shfl(alpha, l4 * 4 + r);
#pragma unroll
      for (int fd = 0; fd < 4; ++fd) o[fd] *= av;
    }

    // p = 2^(s - m); lane-local partial row-sum
    float rs = 0.f;
#pragma unroll
    for (int f = 0; f < 4; ++f)
#pragma unroll
      for (int r = 0; r < 4; ++r) {
        const float pv = __builtin_amdgcn_exp2f(s[f][r] - m);
        s[f][r] = pv;
        rs += pv;
      }
    lsum += rs;

    // P A-fragments (k-slot j of mfma kk -> kv = (kk*2+(j>>2))*16 + l4*4 + (j&3))
    bf16x8 pa[2];
#pragma unroll
    for (int kk = 0; kk < 2; ++kk)
#pragma unroll
      for (int j = 0; j < 8; ++j)
        pa[kk][j] = (bf16)s[kk * 2 + (j >> 2)][j & 3];

    // (e) O += P V : B-frags from swizzled Vt with the SAME permuted-kv mapping
    const char* Vb = Vs + buf * 8192;
    const int sub = (l4 & 1) * 8;
    __builtin_amdgcn_s_setprio(1);
#pragma unroll
    for (int kk = 0; kk < 2; ++kk) {
      const int cr0 = kk * 4 + (l4 >> 1);
#pragma unroll
      for (int fd = 0; fd < 4; ++fd) {
        const int d = fd * 16 + l15;
        const char* row = Vb + d * 128;
        bf16x4 lo = *(const bf16x4*)(row + ((cr0 ^ (d & 7)) << 4) + sub);
        bf16x4 hi = *(const bf16x4*)(row + (((cr0 + 2) ^ (d & 7)) << 4) + sub);
        bf16x8 vb = __builtin_shufflevector(lo, hi, 0, 1, 2, 3, 4, 5, 6, 7);
        o[fd] = __builtin_amdgcn_mfma_f32_16x16x32_bf16(pa[kk], vb, o[fd], 0, 0, 0);
      }
    }
    __builtin_amdgcn_s_setprio(0);

    // (d) late-write next V tile into the other buffer
    if (pre) vt_write(Vs + (buf ^ 1) * 8192, nr0, nr1);

    __syncthreads();
  }

  // epilogue: reduce the 4 lane-group partial row-sums (per q-col)
  lsum += __shfl_xor(lsum, 16);
  lsum += __shfl_xor(lsum, 32);

  // normalize + store (row = q0 + w*16 + l4*4 + r, col = h64 + fd*16 + l15)
  const float inv = 1.0f / lsum;
  f32x4 iv;
#pragma unroll
  for (int r = 0; r < 4; ++r) iv[r] = __shfl(inv, l4 * 4 + r);
  bf16* op = O + ((long)(b * 2048 + q0 + w * 16 + l4 * 4)) * 768 + h64 + l15;
#pragma unroll
  for (int fd = 0; fd < 4; ++fd)
#pragma unroll
    for (int r = 0; r < 4; ++r)
      op[(long)r * 768 + fd * 16] = (bf16)(o[fd][r] * iv[r]);
}

// ---------------- launch ----------------
extern "C" void kernel_launch(void* const* d_in, const int* in_sizes, int n_in,
                              void* d_out, int out_size, void* d_ws, size_t ws_size,
                              hipStream_t stream) {
  const float* x  = (const float*)d_in[0];
  const float* wq = (const float*)d_in[1];
  const float* wp = (const float*)d_in[2];
  float* out = (float*)d_out;
  char* ws = (char*)d_ws;

  bf16* xb   = (bf16*)(ws + 0);
  bf16* wqb  = (bf16*)(ws + 6291456);
  bf16* wpb  = (bf16*)(ws + 9830400);
  bf16* qkvb = (bf16*)(ws + 11010048);
  bf16* ob   = (bf16*)(ws + 29884416);

  cvt3<<<dim3(1024), dim3(256), 0, stream>>>(x, wq, wp, xb, wqb, wpb);
  // qkv = x @ Wqkv^T : M=4096 N=2304 K=768
  gemm_nt<bf16><<<dim3(576), dim3(256), 0, stream>>>(xb, wqb, qkvb, 768, 768, 768, 2304, 32);
  attn_fwd<<<dim3(32, 24), dim3(256), 0, stream>>>(qkvb, ob);
  // out = attn_out @ Wproj^T : M=4096 N=768 K=768, fp32 out
  gemm_nt<float><<<dim3(192), dim3(256), 0, stream>>>(ob, wpb, out, 768, 768, 768, 768, 32);
}

// Round 8
// 154.415 us; speedup vs baseline: 1.4467x; 1.0421x over previous
//
#include <hip/hip_runtime.h>

// Attention fwd: x@Wqkv^T -> flash attn -> @Wproj^T.  bf16 MFMA pipeline, fp32 accum.
// B=2 N=2048 C=768 H=12 Dh=64.

typedef __bf16 bf16;
typedef __attribute__((ext_vector_type(8))) __bf16 bf16x8;
typedef __attribute__((ext_vector_type(4))) __bf16 bf16x4;
typedef __attribute__((ext_vector_type(2))) __bf16 bf16x2;
typedef __attribute__((ext_vector_type(4))) float f32x4;

typedef __attribute__((address_space(1))) void gvoid;
typedef __attribute__((address_space(3))) void lvoid;

__device__ __forceinline__ void gload16(const void* g, void* l) {
  __builtin_amdgcn_global_load_lds((gvoid*)g, (lvoid*)l, 16, 0, 0);
}

// ---------------- fp32 -> bf16 conversion (x, W_qkv, W_proj) ----------------
__global__ __launch_bounds__(256) void cvt3(const float* __restrict__ x,
                                            const float* __restrict__ wq,
                                            const float* __restrict__ wp,
                                            bf16* __restrict__ xb,
                                            bf16* __restrict__ wqb,
                                            bf16* __restrict__ wpb) {
  const int N1 = 786432, N2 = 442368, N3 = 147456;  // float4 counts
  int i = blockIdx.x * 256 + threadIdx.x;
  const int stride = gridDim.x * 256;
  const int total = N1 + N2 + N3;
  for (; i < total; i += stride) {
    const float* src; bf16* dst; int j;
    if (i < N1)           { src = x;  dst = xb;  j = i; }
    else if (i < N1 + N2) { src = wq; dst = wqb; j = i - N1; }
    else                  { src = wp; dst = wpb; j = i - N1 - N2; }
    float4 v = ((const float4*)src)[j];
    bf16x4 o = { (bf16)v.x, (bf16)v.y, (bf16)v.z, (bf16)v.w };
    *(bf16x4*)(dst + (long)j * 4) = o;
  }
}

// ---------------- NT GEMM: C[M,N] = A[M,K] * B[N,K]^T, bf16 in, fp32 accum -----
// Tile BM x BN, BK=64, 256 thr as 2x2 waves (wave owns BM/2 x BN/2).
// 2-phase double-buffered global_load_lds staging; XOR(row&7) chunk swizzle
// applied via pre-swizzled GLOBAL source (linear LDS dest), ds_read_b128 frags.
template <typename OutT, int BM, int BN>
__global__ __launch_bounds__(256, 3) void gemm_nt(const bf16* __restrict__ A,
                                                  const bf16* __restrict__ B,
                                                  OutT* __restrict__ C,
                                                  int K, int lda, int ldb, int ldc,
                                                  int mtiles) {
  constexpr int MI = BM / 32;           // per-wave 16x16 frags in M
  constexpr int NI = BN / 32;           // per-wave 16x16 frags in N
  constexpr int LDSA = BM * 128;        // BM rows x 128B (64 bf16)
  constexpr int LDSB = BN * 128;
  __shared__ __align__(16) char smem[2 * (LDSA + LDSB)];

  const int tid  = threadIdx.x;
  const int lane = tid & 63;
  const int w    = tid >> 6;
  const int wm   = w >> 1, wn = w & 1;
  const int l15  = lane & 15;
  const int l4   = lane >> 4;
  const int m0   = (blockIdx.x % mtiles) * BM;
  const int n0   = (blockIdx.x / mtiles) * BN;
  const int nt   = K >> 6;

  f32x4 acc[MI][NI] = {};

  auto stage = [&](int buf, int t) {
    const int k0 = t << 6;
    char* sA = smem + buf * (LDSA + LDSB);
    char* sB = sA + LDSA;
#pragma unroll
    for (int i = 0; i < BM * 8 / 256; ++i) {
      const int s = i * 256 + tid;             // 16B slot
      const int r = s >> 3;                    // row [0,BM)
      const int c = (s & 7) ^ (r & 7);         // pre-swizzled source chunk
      gload16(A + (long)(m0 + r) * lda + k0 + c * 8, sA + s * 16);
    }
#pragma unroll
    for (int i = 0; i < BN * 8 / 256; ++i) {
      const int s = i * 256 + tid;
      const int r = s >> 3;
      const int c = (s & 7) ^ (r & 7);
      gload16(B + (long)(n0 + r) * ldb + k0 + c * 8, sB + s * 16);
    }
  };

  auto compute = [&](int buf) {
    const char* sA = smem + buf * (LDSA + LDSB);
    const char* sB = sA + LDSA;
#pragma unroll
    for (int kk = 0; kk < 2; ++kk) {
      bf16x8 a[MI], bb[NI];
#pragma unroll
      for (int mi = 0; mi < MI; ++mi) {
        const int row = wm * (BM / 2) + mi * 16 + l15;
        a[mi] = *(const bf16x8*)(sA + row * 128 + (((kk * 4 + l4) ^ (row & 7)) << 4));
      }
#pragma unroll
      for (int ni = 0; ni < NI; ++ni) {
        const int row = wn * (BN / 2) + ni * 16 + l15;
        bb[ni] = *(const bf16x8*)(sB + row * 128 + (((kk * 4 + l4) ^ (row & 7)) << 4));
      }
#pragma unroll
      for (int mi = 0; mi < MI; ++mi)
#pragma unroll
        for (int ni = 0; ni < NI; ++ni)
          acc[mi][ni] = __builtin_amdgcn_mfma_f32_16x16x32_bf16(a[mi], bb[ni], acc[mi][ni], 0, 0, 0);
    }
  };

  stage(0, 0);
  __syncthreads();
  for (int t = 0; t < nt; ++t) {
    if (t + 1 < nt) stage((t + 1) & 1, t + 1);
    compute(t & 1);
    __syncthreads();
  }

  // C/D layout: col = lane&15, row = (lane>>4)*4 + reg
#pragma unroll
  for (int mi = 0; mi < MI; ++mi)
#pragma unroll
    for (int ni = 0; ni < NI; ++ni)
#pragma unroll
      for (int r = 0; r < 4; ++r) {
        const int row = m0 + wm * (BM / 2) + mi * 16 + l4 * 4 + r;
        const int col = n0 + wn * (BN / 2) + ni * 16 + l15;
        C[(long)row * ldc + col] = (OutT)acc[mi][ni][r];
      }
}

// ---------------- flash attention fwd (K through LDS) ------------------------
// grid (32 qtiles, 24 bh); block 256 = 4 waves, wave owns 16 q-rows, full KV.
// K tiles staged ONCE per block via coalesced global_load_lds into XOR-swizzled
// double-buffered LDS (all 4 waves share); A-fragments via ds_read_b128.
// V reg-staged + swizzled transpose writes. Swapped QK^T, in-register P,
// shuffle-free defer-max softmax (exp2 domain).  [R7-verified: 62 µs]
__global__ __launch_bounds__(256, 3) void attn_fwd(const bf16* __restrict__ qkv,
                                                   bf16* __restrict__ O) {
  __shared__ __align__(16) char Ks[16384];  // 2 bufs x K[64 rows][128B] swizzled
  __shared__ __align__(16) char Vs[16384];  // 2 bufs x Vt[64 d][128B kv] swizzled
  const int tid  = threadIdx.x;
  const int lane = tid & 63;
  const int w    = tid >> 6;
  const int l15  = lane & 15;
  const int l4   = lane >> 4;
  const int b    = blockIdx.y / 12;
  const int h    = blockIdx.y % 12;
  const int q0   = blockIdx.x * 64;
  const unsigned base = (unsigned)b * 2048u * 2304u;
  const int h64  = h * 64;
  const unsigned VSTEP = 64u * 2304u;

  // Q fragments, pre-scaled by SCALE*log2(e) = 0.125 * 1.4426950
  bf16x8 qf[2];
  {
    const bf16* qp = qkv + base + (unsigned)(q0 + w * 16 + l15) * 2304u + h64 + l4 * 8;
#pragma unroll
    for (int kk = 0; kk < 2; ++kk) {
      bf16x8 t = *(const bf16x8*)(qp + kk * 32);
#pragma unroll
      for (int j = 0; j < 8; ++j) qf[kk][j] = (bf16)((float)t[j] * 0.18033688f);
    }
  }

  // K staging: 2 rounds x 256 threads of 16B chunks; slot s -> row=s>>3, c'=s&7.
  const int krow0 = tid >> 3;
  const int kc0   = (tid & 7) ^ (krow0 & 7);
  const int krow1 = (256 + tid) >> 3;
  const int kc1   = (tid & 7) ^ (krow1 & 7);
  unsigned koff0 = base + (unsigned)krow0 * 2304u + 768u + h64 + kc0 * 8;
  unsigned koff1 = base + (unsigned)krow1 * 2304u + 768u + h64 + kc1 * 8;

  auto k_stage = [&](int buf) {
    gload16(qkv + koff0, Ks + buf * 8192 + tid * 16);
    gload16(qkv + koff1, Ks + buf * 8192 + 4096 + tid * 16);
    koff0 += VSTEP;
    koff1 += VSTEP;
  };

  // V staging: thread -> kv pair p = tid&31 (rows 2p,2p+1), d-block dblk = tid>>5.
  const int p    = tid & 31;
  const int dblk = tid >> 5;  // [0,8)
  const int pc   = p >> 2;
  const int cw   = (p & 3) * 4;
  unsigned voff = base + (unsigned)(2 * p) * 2304u + 1536u + h64 + dblk * 8;

  auto vt_write = [&](char* W, const bf16x8& r0, const bf16x8& r1) {
#pragma unroll
    for (int j = 0; j < 8; ++j) {
      const int d = dblk * 8 + j;  // d&7 == j
      bf16x2 t2 = { r0[j], r1[j] };
      *(bf16x2*)(W + d * 128 + ((pc ^ j) << 4) + cw) = t2;
    }
  };

  float m = -1e30f, lsum = 0.f;   // lsum = lane-local PARTIAL row-sum
  f32x4 o[4] = {};

  // prologue: stage K tile 0 + V tile 0 into buf 0
  k_stage(0);
  {
    bf16x8 r0 = *(const bf16x8*)(qkv + voff);
    bf16x8 r1 = *(const bf16x8*)(qkv + voff + 2304);
    voff += VSTEP;
    vt_write(Vs, r0, r1);
  }
  __syncthreads();

  for (int t = 0; t < 32; ++t) {
    const int buf = t & 1;
    const bool pre = (t < 31);

    // (a) issue next tile's K stage (async -> LDS) and V reg loads early
    bf16x8 nr0, nr1;
    if (pre) {
      k_stage(buf ^ 1);
      nr0 = *(const bf16x8*)(qkv + voff);
      nr1 = *(const bf16x8*)(qkv + voff + 2304);
      voff += VSTEP;
    }

    // (b) S^T = K Q^T : A-frags from swizzled K LDS (row = f*16+l15, chunk kk*4+l4)
    const char* Kb = Ks + buf * 8192;
    f32x4 s[4];
    __builtin_amdgcn_s_setprio(1);
#pragma unroll
    for (int f = 0; f < 4; ++f) {
      const int row = f * 16 + l15;
      const char* krow = Kb + row * 128;
      bf16x8 k0 = *(const bf16x8*)(krow + (((0 + l4) ^ (row & 7)) << 4));
      bf16x8 k1 = *(const bf16x8*)(krow + (((4 + l4) ^ (row & 7)) << 4));
      f32x4 acc = {};
      acc = __builtin_amdgcn_mfma_f32_16x16x32_bf16(k0, qf[0], acc, 0, 0, 0);
      acc = __builtin_amdgcn_mfma_f32_16x16x32_bf16(k1, qf[1], acc, 0, 0, 0);
      s[f] = acc;
    }
    __builtin_amdgcn_s_setprio(0);

    // (c) shuffle-free steady-state softmax (exp2 domain)
    float tm = s[0][0];
#pragma unroll
    for (int f = 0; f < 4; ++f)
#pragma unroll
      for (int r = 0; r < 4; ++r) tm = fmaxf(tm, s[f][r]);

    if (__any(tm > m + 8.f)) {
      tm = fmaxf(tm, __shfl_xor(tm, 16));
      tm = fmaxf(tm, __shfl_xor(tm, 32));
      const float mn = fmaxf(m, tm);
      const float alpha = __builtin_amdgcn_exp2f(m - mn);
      m = mn;
      lsum *= alpha;
      f32x4 av;
#pragma unroll
      for (int r = 0; r < 4; ++r) av[r] = __shfl(alpha, l4 * 4 + r);
#pragma unroll
      for (int fd = 0; fd < 4; ++fd) o[fd] *= av;
    }

    // p = 2^(s - m); lane-local partial row-sum
    float rs = 0.f;
#pragma unroll
    for (int f = 0; f < 4; ++f)
#pragma unroll
      for (int r = 0; r < 4; ++r) {
        const float pv = __builtin_amdgcn_exp2f(s[f][r] - m);
        s[f][r] = pv;
        rs += pv;
      }
    lsum += rs;

    // P A-fragments (k-slot j of mfma kk -> kv = (kk*2+(j>>2))*16 + l4*4 + (j&3))
    bf16x8 pa[2];
#pragma unroll
    for (int kk = 0; kk < 2; ++kk)
#pragma unroll
      for (int j = 0; j < 8; ++j)
        pa[kk][j] = (bf16)s[kk * 2 + (j >> 2)][j & 3];

    // (e) O += P V : B-frags from swizzled Vt with the SAME permuted-kv mapping
    const char* Vb = Vs + buf * 8192;
    const int sub = (l4 & 1) * 8;
    __builtin_amdgcn_s_setprio(1);
#pragma unroll
    for (int kk = 0; kk < 2; ++kk) {
      const int cr0 = kk * 4 + (l4 >> 1);
#pragma unroll
      for (int fd = 0; fd < 4; ++fd) {
        const int d = fd * 16 + l15;
        const char* row = Vb + d * 128;
        bf16x4 lo = *(const bf16x4*)(row + ((cr0 ^ (d & 7)) << 4) + sub);
        bf16x4 hi = *(const bf16x4*)(row + (((cr0 + 2) ^ (d & 7)) << 4) + sub);
        bf16x8 vb = __builtin_shufflevector(lo, hi, 0, 1, 2, 3, 4, 5, 6, 7);
        o[fd] = __builtin_amdgcn_mfma_f32_16x16x32_bf16(pa[kk], vb, o[fd], 0, 0, 0);
      }
    }
    __builtin_amdgcn_s_setprio(0);

    // (d) late-write next V tile into the other buffer
    if (pre) vt_write(Vs + (buf ^ 1) * 8192, nr0, nr1);

    __syncthreads();
  }

  // epilogue: reduce the 4 lane-group partial row-sums (per q-col)
  lsum += __shfl_xor(lsum, 16);
  lsum += __shfl_xor(lsum, 32);

  // normalize + store (row = q0 + w*16 + l4*4 + r, col = h64 + fd*16 + l15)
  const float inv = 1.0f / lsum;
  f32x4 iv;
#pragma unroll
  for (int r = 0; r < 4; ++r) iv[r] = __shfl(inv, l4 * 4 + r);
  bf16* op = O + ((long)(b * 2048 + q0 + w * 16 + l4 * 4)) * 768 + h64 + l15;
#pragma unroll
  for (int fd = 0; fd < 4; ++fd)
#pragma unroll
    for (int r = 0; r < 4; ++r)
      op[(long)r * 768 + fd * 16] = (bf16)(o[fd][r] * iv[r]);
}

// ---------------- launch ----------------
extern "C" void kernel_launch(void* const* d_in, const int* in_sizes, int n_in,
                              void* d_out, int out_size, void* d_ws, size_t ws_size,
                              hipStream_t stream) {
  const float* x  = (const float*)d_in[0];
  const float* wq = (const float*)d_in[1];
  const float* wp = (const float*)d_in[2];
  float* out = (float*)d_out;
  char* ws = (char*)d_ws;

  bf16* xb   = (bf16*)(ws + 0);
  bf16* wqb  = (bf16*)(ws + 6291456);
  bf16* wpb  = (bf16*)(ws + 9830400);
  bf16* qkvb = (bf16*)(ws + 11010048);
  bf16* ob   = (bf16*)(ws + 29884416);

  cvt3<<<dim3(1024), dim3(256), 0, stream>>>(x, wq, wp, xb, wqb, wpb);
  // qkv = x @ Wqkv^T : M=4096 N=2304 K=768  (64x128 tiles -> 1152 blocks)
  gemm_nt<bf16, 64, 128><<<dim3(64 * 18), dim3(256), 0, stream>>>(
      xb, wqb, qkvb, 768, 768, 768, 2304, 64);
  attn_fwd<<<dim3(32, 24), dim3(256), 0, stream>>>(qkvb, ob);
  // out = attn_out @ Wproj^T : M=4096 N=768 K=768  (64x64 tiles -> 768 blocks)
  gemm_nt<float, 64, 64><<<dim3(64 * 12), dim3(256), 0, stream>>>(
      ob, wpb, out, 768, 768, 768, 768, 64);
}